// Round 7
// baseline (215.712 us; speedup 1.0000x reference)
//
#include <hip/hip_runtime.h>

// MultiHeadAttention fused pipeline for MI355X (gfx950)
// B=2, L=2048, D=1024, H=16, Dh=64.  fp32 in/out, bf16 MFMA compute.

typedef short v8s __attribute__((ext_vector_type(8)));
typedef __bf16 v8bf __attribute__((ext_vector_type(8)));
typedef float v4f __attribute__((ext_vector_type(4)));
typedef float v16f __attribute__((ext_vector_type(16)));
typedef unsigned int uint;

#define DEV static __device__ __forceinline__

DEV short f2bf(float f) {  // RNE float->bf16 (no NaN inputs here)
  unsigned u = __builtin_bit_cast(unsigned, f);
  u += 0x7FFFu + ((u >> 16) & 1u);
  return (short)(u >> 16);
}

DEV uint pack2(float lo, float hi) {  // 2 f32 -> packed 2xbf16 word
  return (uint)(unsigned short)f2bf(lo) | ((uint)(unsigned short)f2bf(hi) << 16);
}

DEV v4f mfma16(v8s a, v8s b, v4f c) {
  return __builtin_amdgcn_mfma_f32_16x16x32_bf16(
      __builtin_bit_cast(v8bf, a), __builtin_bit_cast(v8bf, b), c, 0, 0, 0);
}

DEV v16f mfma32(v8s a, v8s b, v16f c) {
  return __builtin_amdgcn_mfma_f32_32x32x16_bf16(
      __builtin_bit_cast(v8bf, a), __builtin_bit_cast(v8bf, b), c, 0, 0, 0);
}

#define GLDS16(g, l)                                                         \
  __builtin_amdgcn_global_load_lds(                                          \
      (__attribute__((address_space(1))) void*)(g),                          \
      (__attribute__((address_space(3))) void*)(l), 16, 0, 0)

// ---------------- prep: x->bf16 (blocks 0..4095) + weight transpose (4096..8191)
__global__ __launch_bounds__(256) void k_prep(
    const float* __restrict__ x, short* __restrict__ xb,
    const float* __restrict__ wq, const float* __restrict__ wk,
    const float* __restrict__ wv, const float* __restrict__ wo,
    short* __restrict__ wqkvT, short* __restrict__ woT) {
  const int bid = blockIdx.x, tid = threadIdx.x;
  if (bid < 4096) {
    int i = bid * 256 + tid;
    float4 v = reinterpret_cast<const float4*>(x)[i];
    short4 o;
    o.x = f2bf(v.x); o.y = f2bf(v.y); o.z = f2bf(v.z); o.w = f2bf(v.w);
    reinterpret_cast<short4*>(xb)[i] = o;
  } else {
    __shared__ float t[32][33];
    int b2 = bid - 4096;
    int wi = b2 >> 10;
    int rem = b2 & 1023;
    const float* src = (wi == 0) ? wq : (wi == 1) ? wk : (wi == 2) ? wv : wo;
    short* dst = (wi < 3) ? (wqkvT + wi * 1024 * 1024) : woT;
    int n0 = (rem & 31) * 32, k0 = (rem >> 5) * 32;
    int tx = tid & 31, ty = tid >> 5;
#pragma unroll
    for (int i = 0; i < 4; i++)
      t[ty + i * 8][tx] = src[(k0 + ty + i * 8) * 1024 + n0 + tx];
    __syncthreads();
#pragma unroll
    for (int i = 0; i < 4; i++)
      dst[(n0 + ty + i * 8) * 1024 + k0 + tx] = f2bf(t[tx][ty + i * 8]);
  }
}

// ------------- GEMM: C[M,N] = A[M,K] * BT[N,K]^T (+bias)  -------------
// 1D grid, XCD-aware swizzle: xcd=id&7 owns bm in [xcd*4, xcd*4+4) x all bn
// MODE 0: A=x_bf16 [4096,1024], BT=wqkvT [3072,1024];
//         bn 0..7 -> Q (B,H,L,64) scaled; bn 8..15 -> K (B,H,L,64);
//         bn 16..23 -> V^T (B,H,64,L) via LDS transpose (coalesced writes)
// MODE 1: A=ctx [4096,1024],    BT=woT [1024,1024];   out fp32 [4096,1024] + bo
template <int MODE>
__global__ __launch_bounds__(256) void k_gemm(
    const short* __restrict__ A, const short* __restrict__ BT,
    const float* __restrict__ b0, const float* __restrict__ b1,
    const float* __restrict__ b2, short* __restrict__ Qo,
    short* __restrict__ Ko, short* __restrict__ VTo,
    float* __restrict__ outF) {
  constexpr int K = 1024;
  __shared__ short AB[2][128 * 64];  // As=AB[0], Bs=AB[1]; SL aliases AB[0..]
  short* As = AB[0];
  short* Bs = AB[1];
  short* SL = AB[0];  // V^T transpose staging (epilogue only; 16.9KB < 32KB)
  const int tid = threadIdx.x;
  const int w = tid >> 6, lane = tid & 63;
  const int wr = w >> 1, wc = w & 1;
  const int id = blockIdx.x;
  const int pos = id >> 3;
  const int bm = (id & 7) * 4 + (pos & 3);
  const int bn = pos >> 2;
  const int lr = lane & 15, lg = lane >> 4;

  const int rA = tid >> 3;                              // 0..31
  const int cbs = ((tid & 7) * 16) ^ ((rA & 7) << 4);   // swizzled byte col
  const short* pA[4];
  const short* pB[4];
#pragma unroll
  for (int i = 0; i < 4; i++) {
    pA[i] = A + (size_t)(bm * 128 + rA + i * 32) * K + (cbs >> 1);
    pB[i] = BT + (size_t)(bn * 128 + rA + i * 32) * K + (cbs >> 1);
  }

  v4f acc[4][4] = {};
  for (int kt = 0; kt < K / 64; ++kt) {
#pragma unroll
    for (int i = 0; i < 4; i++) {
      GLDS16(pA[i] + kt * 64, As + i * 2048 + w * 512);
      GLDS16(pB[i] + kt * 64, Bs + i * 2048 + w * 512);
    }
    __syncthreads();
#pragma unroll
    for (int ks = 0; ks < 2; ++ks) {
      v8s af[4], bf[4];
#pragma unroll
      for (int mf = 0; mf < 4; mf++) {
        int R = wr * 64 + mf * 16 + lr;
        int byo = (R * 128 + ks * 64 + lg * 16) ^ ((R & 7) << 4);
        af[mf] = *reinterpret_cast<const v8s*>(
            reinterpret_cast<const char*>(As) + byo);
      }
#pragma unroll
      for (int nf = 0; nf < 4; nf++) {
        int R = wc * 64 + nf * 16 + lr;
        int byo = (R * 128 + ks * 64 + lg * 16) ^ ((R & 7) << 4);
        bf[nf] = *reinterpret_cast<const v8s*>(
            reinterpret_cast<const char*>(Bs) + byo);
      }
      __builtin_amdgcn_s_setprio(1);
#pragma unroll
      for (int mf = 0; mf < 4; mf++)
#pragma unroll
        for (int nf = 0; nf < 4; nf++)
          acc[mf][nf] = mfma16(af[mf], bf[nf], acc[mf][nf]);
      __builtin_amdgcn_s_setprio(0);
    }
    __syncthreads();
  }

  if constexpr (MODE == 0) {
    if (bn < 16) {  // Q or K: near-coalesced 32B-chunk scatter
#pragma unroll
      for (int mf = 0; mf < 4; mf++) {
#pragma unroll
        for (int nf = 0; nf < 4; nf++) {
#pragma unroll
          for (int r = 0; r < 4; r++) {
            int mrow = bm * 128 + wr * 64 + mf * 16 + lg * 4 + r;
            int ncol = bn * 128 + wc * 64 + nf * 16 + lr;
            int which = ncol >> 10, d = ncol & 1023;
            float v = acc[mf][nf][r] + ((which == 0) ? b0[d] : b1[d]);
            int h = d >> 6, dh = d & 63;
            int bb = mrow >> 11, lp = mrow & 2047;
            if (which == 0)
              Qo[((size_t)(bb * 16 + h) * 2048 + lp) * 64 + dh] =
                  f2bf(v * 0.18033688011112043f);  // 1/sqrt(Dh) * log2(e)
            else
              Ko[((size_t)(bb * 16 + h) * 2048 + lp) * 64 + dh] = f2bf(v);
          }
        }
      }
    } else {  // V: transpose 128x128 C-tile through LDS, write VT coalesced
      const int bb = bm >> 4;
      const int lp0 = (bm & 15) * 128;
#pragma unroll
      for (int hh = 0; hh < 2; ++hh) {
        if (wc == hh) {
#pragma unroll
          for (int mf = 0; mf < 4; mf++)
#pragma unroll
            for (int nf = 0; nf < 4; nf++)
#pragma unroll
              for (int r = 0; r < 4; r++) {
                int mrow_l = wr * 64 + mf * 16 + lg * 4 + r;  // 0..127 (l)
                int ncol_l = nf * 16 + lr;                    // 0..63 (dv)
                int d = (bn - 16) * 128 + hh * 64 + ncol_l;   // 0..1023
                SL[ncol_l * 132 + mrow_l] = f2bf(acc[mf][nf][r] + b2[d]);
              }
        }
        __syncthreads();
        int h = (bn - 16) * 2 + hh;
        int row = tid >> 2;  // dv 0..63
#pragma unroll
        for (int q = 0; q < 4; q++) {
          int col = ((tid & 3) + q * 4) * 8;  // 4 consecutive 16B chunks
          *reinterpret_cast<v8s*>(
              VTo + ((size_t)(bb * 16 + h) * 64 + row) * 2048 + lp0 + col) =
              *reinterpret_cast<const v8s*>(SL + row * 132 + col);
        }
        __syncthreads();
      }
    }
  } else {
#pragma unroll
    for (int mf = 0; mf < 4; mf++)
#pragma unroll
      for (int nf = 0; nf < 4; nf++)
#pragma unroll
        for (int r = 0; r < 4; r++) {
          int mrow = bm * 128 + wr * 64 + mf * 16 + lg * 4 + r;
          int ncol = bn * 128 + wc * 64 + nf * 16 + lr;
          outF[(size_t)mrow * 1024 + ncol] = acc[mf][nf][r] + b0[ncol];
        }
  }
}

// ------------- causal flash attention (swapped-operand, KVBLK=128) ----------
// QBLK=128 (4 waves x 32 q-rows), KVBLK=128, double-buffered global_load_lds.
// grid (bh=32, y=16): id%8 = bh%8 -> all q-blocks of a head on one XCD (L2).
// S^T = mfma(K, Q): lane owns q = lane&31; O^T = mfma(V^T, P), P exchanged
// in-register via shfl_xor(32) + select (round-4-verified 4-word pattern).
// Row reductions are explicit pairwise TREES (cut ~256 serial cyc/tile).
__global__ __launch_bounds__(256) void k_flash(const short* __restrict__ Qg,
                                               const short* __restrict__ Kg,
                                               const short* __restrict__ VTg,
                                               short* __restrict__ ctx) {
  __shared__ short Kl[2][128 * 64];  // [key 128][d 64] 128B rows, swizzled
  __shared__ short Vl[2][64 * 128];  // [d 64][key 128] 256B rows, swizzled
  const int tid = threadIdx.x, w = tid >> 6, lane = tid & 63;
  const int l31 = lane & 31, hi = lane >> 5;
  const int bh = blockIdx.x;
  const int y = blockIdx.y;
  // co-resident pair (id, id+256) -> (y, y+8) same bh; qt sums uniform (17)
  const int qt = (y < 8) ? y : 23 - y;
  const int q = qt * 128 + w * 32 + l31;  // this lane's q row (global in L)

  // Q fragments (b-operand): qf[dc] = Q[q][dc*16 + hi*8 .. +7]
  v8s qf[4];
  {
    const short* qrow = Qg + ((size_t)bh * 2048 + q) * 64 + hi * 8;
#pragma unroll
    for (int dc = 0; dc < 4; dc++)
      qf[dc] = *reinterpret_cast<const v8s*>(qrow + dc * 16);
  }

  float m = -1e30f, l = 0.f;
  v16f o0 = {}, o1 = {};  // O^T, d = df*32 + (r&3)+8*(r>>2)+4*hi, col q=l31

  const short* kb = Kg + (size_t)bh * 2048 * 64;
  const short* vb = VTg + (size_t)bh * 64 * 2048;

  // staging lane constants
  const int lKr = lane >> 3;                       // K: row-in-group 0..7
  const int lKc = ((lane & 7) ^ lKr) * 8;          // K: swizzled short col
  const int lVr = lane >> 4;                       // V: row-in-group 0..3
  const int w4 = w * 4;

  const int nt = qt + 1;
  int c = 0;
#define STAGE(kt_, cc_)                                                        \
  {                                                                            \
    _Pragma("unroll") for (int i = 0; i < 4; i++) {                            \
      int ii = w4 + i;                                                         \
      GLDS16(kb + (size_t)((kt_)*128 + ii * 8 + lKr) * 64 + lKc,               \
             &Kl[cc_][ii * 512]);                                              \
      int vr = ii * 4 + lVr;                                                   \
      GLDS16(vb + (size_t)vr * 2048 + (kt_)*128 + ((lane & 15) ^ (vr & 7)) * 8,\
             &Vl[cc_][ii * 512]);                                              \
    }                                                                          \
  }
  STAGE(0, 0);

  const int rx = (l31 & 7) << 4;       // xor swizzle for compute reads
  const int krb = l31 * 128;           // K row byte (128B rows)
  const int vrb = l31 * 256;           // V row byte (256B rows)

  for (int kt = 0; kt < nt; ++kt) {
    __syncthreads();  // drains vmcnt -> buf c ready
    if (kt + 1 < nt) STAGE(kt + 1, c ^ 1);

    // ---- QK^T (swapped): s{st} = S^T for keys kt*128 + st*32 + [0..31]
    v16f s0 = {}, s1 = {}, s2 = {}, s3 = {};
    const char* Klc = reinterpret_cast<const char*>(Kl[c]);
    __builtin_amdgcn_s_setprio(1);
#pragma unroll
    for (int dc = 0; dc < 4; dc++) {
      int cb = (dc * 32 + hi * 16) ^ rx;
      v8s k0 = *reinterpret_cast<const v8s*>(Klc + krb + cb);
      v8s k1 = *reinterpret_cast<const v8s*>(Klc + 4096 + krb + cb);
      v8s k2 = *reinterpret_cast<const v8s*>(Klc + 8192 + krb + cb);
      v8s k3 = *reinterpret_cast<const v8s*>(Klc + 12288 + krb + cb);
      s0 = mfma32(k0, qf[dc], s0);
      s1 = mfma32(k1, qf[dc], s1);
      s2 = mfma32(k2, qf[dc], s2);
      s3 = mfma32(k3, qf[dc], s3);
    }
    __builtin_amdgcn_s_setprio(0);

    // ---- causal mask (diagonal tile only)
    if (kt == qt) {
      int kb0 = kt * 128 + 4 * hi;
#pragma unroll
      for (int r = 0; r < 16; r++) {
        int kv = kb0 + (r & 3) + 8 * (r >> 2);
        if (kv > q) s0[r] = -1e30f;
        if (kv + 32 > q) s1[r] = -1e30f;
        if (kv + 64 > q) s2[r] = -1e30f;
        if (kv + 96 > q) s3[r] = -1e30f;
      }
    }

    // ---- online softmax (log2 domain; defer-max THR=8); TREE reductions
    float a[16];
#pragma unroll
    for (int r = 0; r < 16; r++)
      a[r] = fmaxf(fmaxf(s0[r], s1[r]), fmaxf(s2[r], s3[r]));
#pragma unroll
    for (int off = 8; off > 0; off >>= 1)
#pragma unroll
      for (int r = 0; r < 8; r++)
        if (r < off) a[r] = fmaxf(a[r], a[r + off]);
    float pm = a[0];
    pm = fmaxf(pm, __shfl_xor(pm, 32, 64));  // cross-half row max
    if (__any(pm - m > 8.0f)) {
      float mn = fmaxf(m, pm);
      float alpha = __builtin_amdgcn_exp2f(m - mn);
      m = mn;
      l *= alpha;
#pragma unroll
      for (int r = 0; r < 16; r++) { o0[r] *= alpha; o1[r] *= alpha; }
    }
#pragma unroll
    for (int r = 0; r < 16; r++) {
      s0[r] = __builtin_amdgcn_exp2f(s0[r] - m);
      s1[r] = __builtin_amdgcn_exp2f(s1[r] - m);
      s2[r] = __builtin_amdgcn_exp2f(s2[r] - m);
      s3[r] = __builtin_amdgcn_exp2f(s3[r] - m);
    }
    float b[16];
#pragma unroll
    for (int r = 0; r < 16; r++)
      b[r] = (s0[r] + s1[r]) + (s2[r] + s3[r]);
#pragma unroll
    for (int off = 8; off > 0; off >>= 1)
#pragma unroll
      for (int r = 0; r < 8; r++)
        if (r < off) b[r] = b[r] + b[r + off];
    float rs = b[0];
    l += rs + __shfl_xor(rs, 32, 64);

    // ---- pack P to bf16 words: W{st}[t] = (p[2t], p[2t+1])
    uint W0[8], W1[8], W2[8], W3[8];
#pragma unroll
    for (int t = 0; t < 8; t++) {
      W0[t] = pack2(s0[2 * t], s0[2 * t + 1]);
      W1[t] = pack2(s1[2 * t], s1[2 * t + 1]);
      W2[t] = pack2(s2[2 * t], s2[2 * t + 1]);
      W3[t] = pack2(s3[2 * t], s3[2 * t + 1]);
    }

    // ---- PV (swapped): O^T += mfma(VT-frag, P-frag), 8 key-chunks of 16
    // words S0..S3 = Wp[base..base+3]; round-4-verified exchange:
    // hi=0 frag (S0, S1, partner S0, partner S1); sends S2,S3
    // hi=1 frag (partner S2, partner S3, S2, S3); sends S0,S1
    const char* Vlc = reinterpret_cast<const char*>(Vl[c]);
    __builtin_amdgcn_s_setprio(1);
#pragma unroll
    for (int kc = 0; kc < 8; kc++) {
      const uint* Wp = (kc < 2) ? W0 : (kc < 4) ? W1 : (kc < 6) ? W2 : W3;
      int base = (kc & 1) * 4;
      uint S0 = Wp[base + 0], S1 = Wp[base + 1];
      uint S2 = Wp[base + 2], S3 = Wp[base + 3];
      uint x0 = __shfl_xor(hi ? S0 : S2, 32, 64);
      uint x1 = __shfl_xor(hi ? S1 : S3, 32, 64);
      uint4 uf;
      uf.x = hi ? x0 : S0;
      uf.y = hi ? x1 : S1;
      uf.z = hi ? S2 : x0;
      uf.w = hi ? S3 : x1;
      v8s pf = __builtin_bit_cast(v8s, uf);
      int cb = (kc * 32 + hi * 16) ^ rx;
      v8s v0 = *reinterpret_cast<const v8s*>(Vlc + vrb + cb);
      v8s v1 = *reinterpret_cast<const v8s*>(Vlc + 8192 + vrb + cb);
      o0 = mfma32(v0, pf, o0);
      o1 = mfma32(v1, pf, o1);
    }
    __builtin_amdgcn_s_setprio(0);
    c ^= 1;
  }

  // ---- epilogue: ctx[bb*2048 + q][h*64 + d] = O^T[d][q] / l
  const int h = bh & 15, bb = bh >> 4;
  float inv = 1.0f / l;
  short* orow = ctx + ((size_t)(bb * 2048 + q)) * 1024 + h * 64;
#pragma unroll
  for (int df = 0; df < 2; df++) {
#pragma unroll
    for (int g = 0; g < 4; g++) {
      short4 st;
      const v16f& o = df ? o1 : o0;
      st.x = f2bf(o[g * 4 + 0] * inv);
      st.y = f2bf(o[g * 4 + 1] * inv);
      st.z = f2bf(o[g * 4 + 2] * inv);
      st.w = f2bf(o[g * 4 + 3] * inv);
      *reinterpret_cast<short4*>(orow + df * 32 + 8 * g + 4 * hi) = st;
    }
  }
}

extern "C" void kernel_launch(void* const* d_in, const int* in_sizes, int n_in,
                              void* d_out, int out_size, void* d_ws,
                              size_t ws_size, hipStream_t stream) {
  (void)in_sizes; (void)n_in; (void)out_size; (void)ws_size;
  const float* x = (const float*)d_in[0];
  // d_in[1] = causal_mask (implemented analytically)
  const float* wq = (const float*)d_in[2];
  const float* bq = (const float*)d_in[3];
  const float* wk = (const float*)d_in[4];
  const float* bk = (const float*)d_in[5];
  const float* wv = (const float*)d_in[6];
  const float* bv = (const float*)d_in[7];
  const float* wo = (const float*)d_in[8];
  const float* bo = (const float*)d_in[9];

  char* ws = (char*)d_ws;
  short* xb = (short*)(ws);                      // 8 MB (reused as ctx later)
  short* wqkvT = (short*)(ws + (8u << 20));      // 6 MB
  short* woT = (short*)(ws + (14u << 20));       // 2 MB
  short* Qb = (short*)(ws + (16u << 20));        // 8 MB
  short* Kb = (short*)(ws + (24u << 20));        // 8 MB
  short* VTb = (short*)(ws + (32u << 20));       // 8 MB
  short* ctx = xb;                               // alias: xb dead after QKV GEMM
  float* out = (float*)d_out;

  k_prep<<<8192, 256, 0, stream>>>(x, xb, wq, wk, wv, wo, wqkvT, woT);
  k_gemm<0><<<768, 256, 0, stream>>>(xb, wqkvT, bq, bk, bv, Qb, Kb,
                                     VTb, nullptr);
  k_flash<<<dim3(32, 16), 256, 0, stream>>>(Qb, Kb, VTb, ctx);
  k_gemm<1><<<256, 256, 0, stream>>>(ctx, woT, bo, nullptr, nullptr,
                                     nullptr, nullptr, nullptr, out);
}

// Round 9
// 212.803 us; speedup vs baseline: 1.0137x; 1.0137x over previous
//
#include <hip/hip_runtime.h>

// MultiHeadAttention fused pipeline for MI355X (gfx950)
// B=2, L=2048, D=1024, H=16, Dh=64.  fp32 in/out, bf16 MFMA compute.

typedef short v8s __attribute__((ext_vector_type(8)));
typedef __bf16 v8bf __attribute__((ext_vector_type(8)));
typedef float v4f __attribute__((ext_vector_type(4)));
typedef float v16f __attribute__((ext_vector_type(16)));
typedef unsigned int uint;

#define DEV static __device__ __forceinline__

DEV short f2bf(float f) {  // RNE float->bf16 (no NaN inputs here)
  unsigned u = __builtin_bit_cast(unsigned, f);
  u += 0x7FFFu + ((u >> 16) & 1u);
  return (short)(u >> 16);
}

DEV uint pk2(float lo, float hi) {  // 2 f32 -> packed 2xbf16 (v_cvt_pk path)
  unsigned short ul = __builtin_bit_cast(unsigned short, (__bf16)lo);
  unsigned short uh = __builtin_bit_cast(unsigned short, (__bf16)hi);
  return (uint)ul | ((uint)uh << 16);
}

DEV v4f mfma16(v8s a, v8s b, v4f c) {
  return __builtin_amdgcn_mfma_f32_16x16x32_bf16(
      __builtin_bit_cast(v8bf, a), __builtin_bit_cast(v8bf, b), c, 0, 0, 0);
}

DEV v16f mfma32(v8s a, v8s b, v16f c) {
  return __builtin_amdgcn_mfma_f32_32x32x16_bf16(
      __builtin_bit_cast(v8bf, a), __builtin_bit_cast(v8bf, b), c, 0, 0, 0);
}

#define GLDS16(g, l)                                                         \
  __builtin_amdgcn_global_load_lds(                                          \
      (__attribute__((address_space(1))) void*)(g),                          \
      (__attribute__((address_space(3))) void*)(l), 16, 0, 0)

// ---------------- prep: x->bf16 (blocks 0..4095) + weight transpose (4096..8191)
__global__ __launch_bounds__(256) void k_prep(
    const float* __restrict__ x, short* __restrict__ xb,
    const float* __restrict__ wq, const float* __restrict__ wk,
    const float* __restrict__ wv, const float* __restrict__ wo,
    short* __restrict__ wqkvT, short* __restrict__ woT) {
  const int bid = blockIdx.x, tid = threadIdx.x;
  if (bid < 4096) {
    int i = bid * 256 + tid;
    float4 v = reinterpret_cast<const float4*>(x)[i];
    short4 o;
    o.x = f2bf(v.x); o.y = f2bf(v.y); o.z = f2bf(v.z); o.w = f2bf(v.w);
    reinterpret_cast<short4*>(xb)[i] = o;
  } else {
    __shared__ float t[32][33];
    int b2 = bid - 4096;
    int wi = b2 >> 10;
    int rem = b2 & 1023;
    const float* src = (wi == 0) ? wq : (wi == 1) ? wk : (wi == 2) ? wv : wo;
    short* dst = (wi < 3) ? (wqkvT + wi * 1024 * 1024) : woT;
    int n0 = (rem & 31) * 32, k0 = (rem >> 5) * 32;
    int tx = tid & 31, ty = tid >> 5;
#pragma unroll
    for (int i = 0; i < 4; i++)
      t[ty + i * 8][tx] = src[(k0 + ty + i * 8) * 1024 + n0 + tx];
    __syncthreads();
#pragma unroll
    for (int i = 0; i < 4; i++)
      dst[(n0 + ty + i * 8) * 1024 + k0 + tx] = f2bf(t[tx][ty + i * 8]);
  }
}

// ------------- GEMM: C[M,N] = A[M,K] * BT[N,K]^T (+bias)  -------------
// 1D grid, XCD-aware swizzle: xcd=id&7 owns bm in [xcd*4, xcd*4+4) x all bn
// MODE 0: A=x_bf16 [4096,1024], BT=wqkvT [3072,1024];
//         bn 0..7 -> Q (B,H,L,64) scaled; bn 8..15 -> K (B,H,L,64);
//         bn 16..23 -> V^T (B,H,64,L) via LDS transpose (coalesced writes)
// MODE 1: A=ctx [4096,1024],    BT=woT [1024,1024];   out fp32 [4096,1024] + bo
template <int MODE>
__global__ __launch_bounds__(256) void k_gemm(
    const short* __restrict__ A, const short* __restrict__ BT,
    const float* __restrict__ b0, const float* __restrict__ b1,
    const float* __restrict__ b2, short* __restrict__ Qo,
    short* __restrict__ Ko, short* __restrict__ VTo,
    float* __restrict__ outF) {
  constexpr int K = 1024;
  __shared__ short AB[2][128 * 64];  // As=AB[0], Bs=AB[1]; SL aliases AB[0..]
  short* As = AB[0];
  short* Bs = AB[1];
  short* SL = AB[0];  // V^T transpose staging (epilogue only; 16.9KB < 32KB)
  const int tid = threadIdx.x;
  const int w = tid >> 6, lane = tid & 63;
  const int wr = w >> 1, wc = w & 1;
  const int id = blockIdx.x;
  const int pos = id >> 3;
  const int bm = (id & 7) * 4 + (pos & 3);
  const int bn = pos >> 2;
  const int lr = lane & 15, lg = lane >> 4;

  const int rA = tid >> 3;                              // 0..31
  const int cbs = ((tid & 7) * 16) ^ ((rA & 7) << 4);   // swizzled byte col
  const short* pA[4];
  const short* pB[4];
#pragma unroll
  for (int i = 0; i < 4; i++) {
    pA[i] = A + (size_t)(bm * 128 + rA + i * 32) * K + (cbs >> 1);
    pB[i] = BT + (size_t)(bn * 128 + rA + i * 32) * K + (cbs >> 1);
  }

  v4f acc[4][4] = {};
  for (int kt = 0; kt < K / 64; ++kt) {
#pragma unroll
    for (int i = 0; i < 4; i++) {
      GLDS16(pA[i] + kt * 64, As + i * 2048 + w * 512);
      GLDS16(pB[i] + kt * 64, Bs + i * 2048 + w * 512);
    }
    __syncthreads();
#pragma unroll
    for (int ks = 0; ks < 2; ++ks) {
      v8s af[4], bf[4];
#pragma unroll
      for (int mf = 0; mf < 4; mf++) {
        int R = wr * 64 + mf * 16 + lr;
        int byo = (R * 128 + ks * 64 + lg * 16) ^ ((R & 7) << 4);
        af[mf] = *reinterpret_cast<const v8s*>(
            reinterpret_cast<const char*>(As) + byo);
      }
#pragma unroll
      for (int nf = 0; nf < 4; nf++) {
        int R = wc * 64 + nf * 16 + lr;
        int byo = (R * 128 + ks * 64 + lg * 16) ^ ((R & 7) << 4);
        bf[nf] = *reinterpret_cast<const v8s*>(
            reinterpret_cast<const char*>(Bs) + byo);
      }
      __builtin_amdgcn_s_setprio(1);
#pragma unroll
      for (int mf = 0; mf < 4; mf++)
#pragma unroll
        for (int nf = 0; nf < 4; nf++)
          acc[mf][nf] = mfma16(af[mf], bf[nf], acc[mf][nf]);
      __builtin_amdgcn_s_setprio(0);
    }
    __syncthreads();
  }

  if constexpr (MODE == 0) {
    if (bn < 16) {  // Q or K: near-coalesced 32B-chunk scatter
#pragma unroll
      for (int mf = 0; mf < 4; mf++) {
#pragma unroll
        for (int nf = 0; nf < 4; nf++) {
#pragma unroll
          for (int r = 0; r < 4; r++) {
            int mrow = bm * 128 + wr * 64 + mf * 16 + lg * 4 + r;
            int ncol = bn * 128 + wc * 64 + nf * 16 + lr;
            int which = ncol >> 10, d = ncol & 1023;
            float v = acc[mf][nf][r] + ((which == 0) ? b0[d] : b1[d]);
            int h = d >> 6, dh = d & 63;
            int bb = mrow >> 11, lp = mrow & 2047;
            if (which == 0)
              Qo[((size_t)(bb * 16 + h) * 2048 + lp) * 64 + dh] =
                  f2bf(v * 0.18033688011112043f);  // 1/sqrt(Dh) * log2(e)
            else
              Ko[((size_t)(bb * 16 + h) * 2048 + lp) * 64 + dh] = f2bf(v);
          }
        }
      }
    } else {  // V: transpose 128x128 C-tile through LDS, write VT coalesced
      const int bb = bm >> 4;
      const int lp0 = (bm & 15) * 128;
#pragma unroll
      for (int hh = 0; hh < 2; ++hh) {
        if (wc == hh) {
#pragma unroll
          for (int mf = 0; mf < 4; mf++)
#pragma unroll
            for (int nf = 0; nf < 4; nf++)
#pragma unroll
              for (int r = 0; r < 4; r++) {
                int mrow_l = wr * 64 + mf * 16 + lg * 4 + r;  // 0..127 (l)
                int ncol_l = nf * 16 + lr;                    // 0..63 (dv)
                int d = (bn - 16) * 128 + hh * 64 + ncol_l;   // 0..1023
                SL[ncol_l * 132 + mrow_l] = f2bf(acc[mf][nf][r] + b2[d]);
              }
        }
        __syncthreads();
        int h = (bn - 16) * 2 + hh;
        int row = tid >> 2;  // dv 0..63
#pragma unroll
        for (int q = 0; q < 4; q++) {
          int col = ((tid & 3) + q * 4) * 8;  // 4 consecutive 16B chunks
          *reinterpret_cast<v8s*>(
              VTo + ((size_t)(bb * 16 + h) * 64 + row) * 2048 + lp0 + col) =
              *reinterpret_cast<const v8s*>(SL + row * 132 + col);
        }
        __syncthreads();
      }
    }
  } else {
#pragma unroll
    for (int mf = 0; mf < 4; mf++)
#pragma unroll
      for (int nf = 0; nf < 4; nf++)
#pragma unroll
        for (int r = 0; r < 4; r++) {
          int mrow = bm * 128 + wr * 64 + mf * 16 + lg * 4 + r;
          int ncol = bn * 128 + wc * 64 + nf * 16 + lr;
          outF[(size_t)mrow * 1024 + ncol] = acc[mf][nf][r] + b0[ncol];
        }
  }
}

// ------------- causal flash attention (swapped-operand, KVBLK=128) ----------
// QBLK=128 (4 waves x 32 q-rows), KVBLK=128, double-buffered global_load_lds.
// grid (bh=32, y=16): id%8 = bh%8 -> all q-blocks of a head on one XCD (L2).
// S^T = mfma(K, Q): lane owns q = lane&31; O^T = mfma(V^T, P), P exchanged
// in-register via shfl_xor(32) + select (round-4-verified 4-word pattern).
// Softmax denominator computed on the MATRIX pipe: l_acc = mfma(ones, P).
__global__ __launch_bounds__(256) void k_flash(const short* __restrict__ Qg,
                                               const short* __restrict__ Kg,
                                               const short* __restrict__ VTg,
                                               short* __restrict__ ctx) {
  __shared__ short Kl[2][128 * 64];  // [key 128][d 64] 128B rows, swizzled
  __shared__ short Vl[2][64 * 128];  // [d 64][key 128] 256B rows, swizzled
  const int tid = threadIdx.x, w = tid >> 6, lane = tid & 63;
  const int l31 = lane & 31, hi = lane >> 5;
  const int bh = blockIdx.x;
  const int y = blockIdx.y;
  // co-resident pair (id, id+256) -> (y, y+8) same bh; qt sums uniform (17)
  const int qt = (y < 8) ? y : 23 - y;
  const int q = qt * 128 + w * 32 + l31;  // this lane's q row (global in L)

  // Q fragments (b-operand): qf[dc] = Q[q][dc*16 + hi*8 .. +7]
  v8s qf[4];
  {
    const short* qrow = Qg + ((size_t)bh * 2048 + q) * 64 + hi * 8;
#pragma unroll
    for (int dc = 0; dc < 4; dc++)
      qf[dc] = *reinterpret_cast<const v8s*>(qrow + dc * 16);
  }

  float m = -1e30f;
  v16f o0 = {}, o1 = {};  // O^T, d = df*32 + (r&3)+8*(r>>2)+4*hi, col q=l31
  v16f lA = {};           // denominator accumulator: lA[0] = sum_k P[k][q]

  const uint4 onesu = {0x3F803F80u, 0x3F803F80u, 0x3F803F80u, 0x3F803F80u};
  const v8s vone = __builtin_bit_cast(v8s, onesu);

  const short* kb = Kg + (size_t)bh * 2048 * 64;
  const short* vb = VTg + (size_t)bh * 64 * 2048;

  // staging lane constants
  const int lKr = lane >> 3;                       // K: row-in-group 0..7
  const int lKc = ((lane & 7) ^ lKr) * 8;          // K: swizzled short col
  const int lVr = lane >> 4;                       // V: row-in-group 0..3
  const int w4 = w * 4;

  const int nt = qt + 1;
  int c = 0;
#define STAGE(kt_, cc_)                                                        \
  {                                                                            \
    _Pragma("unroll") for (int i = 0; i < 4; i++) {                            \
      int ii = w4 + i;                                                         \
      GLDS16(kb + (size_t)((kt_)*128 + ii * 8 + lKr) * 64 + lKc,               \
             &Kl[cc_][ii * 512]);                                              \
      int vr = ii * 4 + lVr;                                                   \
      GLDS16(vb + (size_t)vr * 2048 + (kt_)*128 + ((lane & 15) ^ (vr & 7)) * 8,\
             &Vl[cc_][ii * 512]);                                              \
    }                                                                          \
  }
  STAGE(0, 0);

  const int rx = (l31 & 7) << 4;       // xor swizzle for compute reads
  const int krb = l31 * 128;           // K row byte (128B rows)
  const int vrb = l31 * 256;           // V row byte (256B rows)

  for (int kt = 0; kt < nt; ++kt) {
    __syncthreads();  // drains vmcnt -> buf c ready
    if (kt + 1 < nt) STAGE(kt + 1, c ^ 1);

    // ---- QK^T (swapped): s{st} = S^T for keys kt*128 + st*32 + [0..31]
    v16f s0 = {}, s1 = {}, s2 = {}, s3 = {};
    const char* Klc = reinterpret_cast<const char*>(Kl[c]);
    __builtin_amdgcn_s_setprio(1);
#pragma unroll
    for (int dc = 0; dc < 4; dc++) {
      int cb = (dc * 32 + hi * 16) ^ rx;
      v8s k0 = *reinterpret_cast<const v8s*>(Klc + krb + cb);
      v8s k1 = *reinterpret_cast<const v8s*>(Klc + 4096 + krb + cb);
      v8s k2 = *reinterpret_cast<const v8s*>(Klc + 8192 + krb + cb);
      v8s k3 = *reinterpret_cast<const v8s*>(Klc + 12288 + krb + cb);
      s0 = mfma32(k0, qf[dc], s0);
      s1 = mfma32(k1, qf[dc], s1);
      s2 = mfma32(k2, qf[dc], s2);
      s3 = mfma32(k3, qf[dc], s3);
    }
    __builtin_amdgcn_s_setprio(0);

    // ---- causal mask (diagonal tile only)
    if (kt == qt) {
      int kb0 = kt * 128 + 4 * hi;
#pragma unroll
      for (int r = 0; r < 16; r++) {
        int kv = kb0 + (r & 3) + 8 * (r >> 2);
        if (kv > q) s0[r] = -1e30f;
        if (kv + 32 > q) s1[r] = -1e30f;
        if (kv + 64 > q) s2[r] = -1e30f;
        if (kv + 96 > q) s3[r] = -1e30f;
      }
    }

    // ---- row max: 4 parallel accumulators of 4-way (v_max3-friendly) maxes
    float pp[4];
#pragma unroll
    for (int r = 0; r < 4; r++)
      pp[r] = fmaxf(fmaxf(fmaxf(s0[r], s1[r]), s2[r]), s3[r]);
#pragma unroll
    for (int r = 4; r < 16; r++)
      pp[r & 3] =
          fmaxf(pp[r & 3], fmaxf(fmaxf(fmaxf(s0[r], s1[r]), s2[r]), s3[r]));
    float pm = fmaxf(fmaxf(pp[0], pp[1]), fmaxf(pp[2], pp[3]));
    pm = fmaxf(pm, __shfl_xor(pm, 32, 64));  // cross-half row max

    // ---- defer-max rescale (THR=8); lA[0] carries the denominator
    if (__any(pm - m > 8.0f)) {
      float mn = fmaxf(m, pm);
      float alpha = __builtin_amdgcn_exp2f(m - mn);
      m = mn;
      lA[0] *= alpha;
#pragma unroll
      for (int r = 0; r < 16; r++) { o0[r] *= alpha; o1[r] *= alpha; }
    }
#pragma unroll
    for (int r = 0; r < 16; r++) {
      s0[r] = __builtin_amdgcn_exp2f(s0[r] - m);
      s1[r] = __builtin_amdgcn_exp2f(s1[r] - m);
      s2[r] = __builtin_amdgcn_exp2f(s2[r] - m);
      s3[r] = __builtin_amdgcn_exp2f(s3[r] - m);
    }

    // ---- pack P to bf16 words: W{st}[t] = (p[2t], p[2t+1])
    uint W0[8], W1[8], W2[8], W3[8];
#pragma unroll
    for (int t = 0; t < 8; t++) {
      W0[t] = pk2(s0[2 * t], s0[2 * t + 1]);
      W1[t] = pk2(s1[2 * t], s1[2 * t + 1]);
      W2[t] = pk2(s2[2 * t], s2[2 * t + 1]);
      W3[t] = pk2(s3[2 * t], s3[2 * t + 1]);
    }

    // ---- PV (swapped): O^T += mfma(VT-frag, P-frag), 8 key-chunks of 16
    // words S0..S3 = Wp[base..base+3]; round-4-verified exchange:
    // hi=0 frag (S0, S1, partner S0, partner S1); sends S2,S3
    // hi=1 frag (partner S2, partner S3, S2, S3); sends S0,S1
    // l_acc gets the same P fragments against an all-ones A operand.
    const char* Vlc = reinterpret_cast<const char*>(Vl[c]);
    __builtin_amdgcn_s_setprio(1);
#pragma unroll
    for (int kc = 0; kc < 8; kc++) {
      const uint* Wp = (kc < 2) ? W0 : (kc < 4) ? W1 : (kc < 6) ? W2 : W3;
      int base = (kc & 1) * 4;
      uint S0 = Wp[base + 0], S1 = Wp[base + 1];
      uint S2 = Wp[base + 2], S3 = Wp[base + 3];
      uint x0 = __shfl_xor(hi ? S0 : S2, 32, 64);
      uint x1 = __shfl_xor(hi ? S1 : S3, 32, 64);
      uint4 uf;
      uf.x = hi ? x0 : S0;
      uf.y = hi ? x1 : S1;
      uf.z = hi ? S2 : x0;
      uf.w = hi ? S3 : x1;
      v8s pf = __builtin_bit_cast(v8s, uf);
      int cb = (kc * 32 + hi * 16) ^ rx;
      v8s v0 = *reinterpret_cast<const v8s*>(Vlc + vrb + cb);
      v8s v1 = *reinterpret_cast<const v8s*>(Vlc + 8192 + vrb + cb);
      o0 = mfma32(v0, pf, o0);
      o1 = mfma32(v1, pf, o1);
      lA = mfma32(vone, pf, lA);
    }
    __builtin_amdgcn_s_setprio(0);
    c ^= 1;
  }

  // ---- epilogue: ctx[bb*2048 + q][h*64 + d] = O^T[d][q] / l
  const int h = bh & 15, bb = bh >> 4;
  float inv = 1.0f / lA[0];
  short* orow = ctx + ((size_t)(bb * 2048 + q)) * 1024 + h * 64;
#pragma unroll
  for (int df = 0; df < 2; df++) {
#pragma unroll
    for (int g = 0; g < 4; g++) {
      short4 st;
      const v16f& o = df ? o1 : o0;
      st.x = f2bf(o[g * 4 + 0] * inv);
      st.y = f2bf(o[g * 4 + 1] * inv);
      st.z = f2bf(o[g * 4 + 2] * inv);
      st.w = f2bf(o[g * 4 + 3] * inv);
      *reinterpret_cast<short4*>(orow + df * 32 + 8 * g + 4 * hi) = st;
    }
  }
}

extern "C" void kernel_launch(void* const* d_in, const int* in_sizes, int n_in,
                              void* d_out, int out_size, void* d_ws,
                              size_t ws_size, hipStream_t stream) {
  (void)in_sizes; (void)n_in; (void)out_size; (void)ws_size;
  const float* x = (const float*)d_in[0];
  // d_in[1] = causal_mask (implemented analytically)
  const float* wq = (const float*)d_in[2];
  const float* bq = (const float*)d_in[3];
  const float* wk = (const float*)d_in[4];
  const float* bk = (const float*)d_in[5];
  const float* wv = (const float*)d_in[6];
  const float* bv = (const float*)d_in[7];
  const float* wo = (const float*)d_in[8];
  const float* bo = (const float*)d_in[9];

  char* ws = (char*)d_ws;
  short* xb = (short*)(ws);                      // 8 MB (reused as ctx later)
  short* wqkvT = (short*)(ws + (8u << 20));      // 6 MB
  short* woT = (short*)(ws + (14u << 20));       // 2 MB
  short* Qb = (short*)(ws + (16u << 20));        // 8 MB
  short* Kb = (short*)(ws + (24u << 20));        // 8 MB
  short* VTb = (short*)(ws + (32u << 20));       // 8 MB
  short* ctx = xb;                               // alias: xb dead after QKV GEMM
  float* out = (float*)d_out;

  k_prep<<<8192, 256, 0, stream>>>(x, xb, wq, wk, wv, wo, wqkvT, woT);
  k_gemm<0><<<768, 256, 0, stream>>>(xb, wqkvT, bq, bk, bv, Qb, Kb,
                                     VTb, nullptr);
  k_flash<<<dim3(32, 16), 256, 0, stream>>>(Qb, Kb, VTb, ctx);
  k_gemm<1><<<256, 256, 0, stream>>>(ctx, woT, bo, nullptr, nullptr,
                                     nullptr, nullptr, nullptr, out);
}